// Round 15
// baseline (84.640 us; speedup 1.0000x reference)
//
#include <hip/hip_runtime.h>
#include <hip/hip_bf16.h>
#include <math.h>

typedef __bf16 bf16;
typedef __bf16 bf16x8 __attribute__((ext_vector_type(8)));
typedef float floatx4 __attribute__((ext_vector_type(4)));

#define NB 8
#define NS 1024
#define ND 512
#define NH 8
#define NDH 64
#define NBH 64
#define MROWS 8192
#define N3 1536
#define KSCL 0.18033688f  // 0.125 * log2(e): folded into K so exp(s/8)=exp2(s')

#define GLD16(src, dst)                                                            \
    __builtin_amdgcn_global_load_lds(                                              \
        (const __attribute__((address_space(1))) void*)(src),                      \
        (__attribute__((address_space(3))) void*)(dst), 16, 0, 0)

static __device__ __forceinline__ floatx4 mfma16(bf16x8 a, bf16x8 b, floatx4 c) {
    return __builtin_amdgcn_mfma_f32_16x16x32_bf16(a, b, c, 0, 0, 0);
}

// fast 2^x: raw v_exp_f32 (inputs here are bounded [0, ~12] — no edge cases)
static __device__ __forceinline__ float fexp2(float x) {
#if __has_builtin(__builtin_amdgcn_exp2f)
    return __builtin_amdgcn_exp2f(x);
#else
    return __expf(x * 0.69314718f);
#endif
}

static __device__ __forceinline__ unsigned pack2(float lo, float hi) {
    union { bf16 h[2]; unsigned u; } u;
    u.h[0] = (bf16)lo; u.h[1] = (bf16)hi;
    return u.u;
}

// non-volatile — pure value ops, scheduler may interleave chains
static __device__ __forceinline__ void plane32(unsigned &a, unsigned &b) {
    asm("v_permlane32_swap_b32 %0, %1" : "+v"(a), "+v"(b));
}
static __device__ __forceinline__ void plane16(unsigned &a, unsigned &b) {
    asm("v_permlane16_swap_b32 %0, %1" : "+v"(a), "+v"(b));
}

// ---- prep: [0,2048) x fp32->bf16 (+ zero BN accum); [2048,2816) W transpose+convert ----
__global__ void prep(const float* __restrict__ x, bf16* __restrict__ xb,
                     float* __restrict__ bnSum, const float* __restrict__ Wq,
                     const float* __restrict__ Wk, const float* __restrict__ Wv,
                     bf16* __restrict__ Wb) {
    __shared__ float tl[32][33];
    int bid = blockIdx.x;
    int t = threadIdx.x;
    if (bid < 2048) {
        if (bid == 0) {
            ((float4*)bnSum)[t] = make_float4(0.f, 0.f, 0.f, 0.f);  // 1024 floats
        }
        int i = (bid * 256 + t) * 8;
        float4 a = *(const float4*)&x[i];
        float4 b = *(const float4*)&x[i + 4];
        bf16 o[8] = {(bf16)a.x, (bf16)a.y, (bf16)a.z, (bf16)a.w,
                     (bf16)b.x, (bf16)b.y, (bf16)b.z, (bf16)b.w};
        *(bf16x8*)&xb[i] = *(bf16x8*)o;
    } else {
        int wbid = bid - 2048;
        int mat = wbid >> 8;          // 0..2
        int bx = wbid & 15;           // d0 / 32
        int by = (wbid >> 4) & 15;    // e0 / 32
        const float* W = mat == 0 ? Wq : (mat == 1 ? Wk : Wv);
        int d0 = bx * 32, e0 = by * 32;
        int tx = t & 31, ty = t >> 5;  // 32 x 8
#pragma unroll
        for (int i = 0; i < 4; i++) tl[ty * 4 + i][tx] = W[(d0 + ty * 4 + i) * ND + e0 + tx];
        __syncthreads();
#pragma unroll
        for (int i = 0; i < 4; i++)
            Wb[(mat * ND + e0 + ty * 4 + i) * ND + d0 + tx] = (bf16)tl[tx][ty * 4 + i];
    }
}

// ---------------- GEMM1: QKV = relu(xb @ Wb^T + b), K-cols pre-scaled by KSCL ------------
__launch_bounds__(256)
__global__ void gemm1(const bf16* __restrict__ xb, const bf16* __restrict__ Wb,
                      const float* __restrict__ bq, const float* __restrict__ bk,
                      const float* __restrict__ bv, bf16* __restrict__ QKV) {
    __shared__ __align__(16) bf16 As[128 * 64];
    __shared__ __align__(16) bf16 Bs[128 * 64];
    int t = threadIdx.x, lane = t & 63, w = t >> 6;
    int wr = w >> 1, wc = w & 1;
    int lr = lane & 15, lg = lane >> 4;
    int row0 = blockIdx.x * 128, col0 = blockIdx.y * 128;
    int srow = t >> 3, sj = t & 7;
    floatx4 acc[4][4] = {};
    for (int k0 = 0; k0 < ND; k0 += 64) {
        __syncthreads();
#pragma unroll
        for (int it = 0; it < 4; it++) {
            int row = it * 32 + srow;
            int j = sj ^ (row & 7);
            GLD16(&xb[(size_t)(row0 + row) * ND + k0 + j * 8], &As[(it * 256 + w * 64) * 8]);
            GLD16(&Wb[(size_t)(col0 + row) * ND + k0 + j * 8], &Bs[(it * 256 + w * 64) * 8]);
        }
        __syncthreads();
        bf16x8 af[2][4], bfr[2][4];
#pragma unroll
        for (int ks = 0; ks < 2; ks++) {
#pragma unroll
            for (int mt = 0; mt < 4; mt++)
                af[ks][mt] = *(const bf16x8*)&As[(wr * 64 + mt * 16 + lr) * 64 +
                                                 ((ks * 4 + lg) ^ (lr & 7)) * 8];
#pragma unroll
            for (int nt = 0; nt < 4; nt++)
                bfr[ks][nt] = *(const bf16x8*)&Bs[(wc * 64 + nt * 16 + lr) * 64 +
                                                  ((ks * 4 + lg) ^ (lr & 7)) * 8];
        }
#pragma unroll
        for (int ks = 0; ks < 2; ks++)
#pragma unroll
            for (int mt = 0; mt < 4; mt++)
#pragma unroll
                for (int nt = 0; nt < 4; nt++)
                    acc[mt][nt] = mfma16(af[ks][mt], bfr[ks][nt], acc[mt][nt]);
    }
#pragma unroll
    for (int mt = 0; mt < 4; mt++)
#pragma unroll
        for (int nt = 0; nt < 4; nt++) {
            int col = col0 + wc * 64 + nt * 16 + lr;
            float bias = col < 512 ? bq[col] : (col < 1024 ? bk[col - 512] : bv[col - 1024]);
            float scl = (col >= 512 && col < 1024) ? KSCL : 1.0f;
#pragma unroll
            for (int r = 0; r < 4; r++) {
                int row = row0 + wr * 64 + mt * 16 + lg * 4 + r;
                float v = acc[mt][nt][r] + bias;
                v = v > 0.f ? v : 0.f;
                v *= scl;
                QKV[(size_t)row * N3 + col] = (bf16)v;
            }
        }
}

// ---- colsum + V->fragment blobs + K->fragment blobs (k-tile 128, grid (64,8)):
//      rc[k]=1/sum_q exp2(s'); VB/KB hold MFMA fragments for the fused pass ---------------
__launch_bounds__(256)
__global__ void attn_colsum_vt(const bf16* __restrict__ QKV, bf16* __restrict__ VB,
                               bf16* __restrict__ KB) {
    __shared__ __align__(16) bf16 Qs[128 * 64];  // 16 KB
    __shared__ float rcS[128];
    int bh = blockIdx.x, b = bh >> 3, h = bh & 7;
    int kbidx = blockIdx.y;
    int k0 = kbidx * 128;
    int t = threadIdx.x, lane = t & 63, w = t >> 6;
    int lr = lane & 15, lg = lane >> 4;
    int srow = t >> 3, sj = t & 7;
    // K fragments (A operand of swapped mfma) held in registers for whole kernel
    bf16x8 kf[2][2];
#pragma unroll
    for (int tt = 0; tt < 2; tt++)
#pragma unroll
        for (int s = 0; s < 2; s++)
            kf[tt][s] = *(const bf16x8*)&QKV[(size_t)(b * NS + k0 + w * 32 + tt * 16 + lr) * N3 +
                                             512 + h * NDH + s * 32 + lg * 8];
    // dump K fragments to KB blobs (identical lane layout to fused's kfr, w == kt)
#pragma unroll
    for (int tt = 0; tt < 2; tt++)
#pragma unroll
        for (int s = 0; s < 2; s++)
            *(bf16x8*)&KB[(size_t)((((bh * 8 + kbidx) * 4 + w) * 4) + tt * 2 + s) * 512 +
                          lane * 8] = kf[tt][s];
    floatx4 csum[2] = {};
    const floatx4 zf = {};
    for (int qc = 0; qc < 8; qc++) {
        __syncthreads();
#pragma unroll
        for (int it = 0; it < 4; it++) {
            int row = it * 32 + srow;
            int j = sj ^ (row & 7);
            GLD16(&QKV[(size_t)(b * NS + qc * 128 + row) * N3 + h * NDH + j * 8],
                  &Qs[(it * 256 + w * 64) * 8]);
        }
        __syncthreads();
        __builtin_amdgcn_s_setprio(1);  // favor compute-phase waves vs staging-phase block
#pragma unroll
        for (int qt = 0; qt < 8; qt++) {
            bf16x8 qb0 = *(const bf16x8*)&Qs[(qt * 16 + lr) * 64 + (lg ^ (lr & 7)) * 8];
            bf16x8 qb1 = *(const bf16x8*)&Qs[(qt * 16 + lr) * 64 + ((4 + lg) ^ (lr & 7)) * 8];
#pragma unroll
            for (int tt = 0; tt < 2; tt++) {
                floatx4 a = mfma16(kf[tt][0], qb0, zf);
                a = mfma16(kf[tt][1], qb1, a);
#pragma unroll
                for (int r = 0; r < 4; r++) csum[tt][r] += fexp2(a[r]);
            }
        }
        __builtin_amdgcn_s_setprio(0);
    }
#pragma unroll
    for (int tt = 0; tt < 2; tt++)
#pragma unroll
        for (int r = 0; r < 4; r++) {
            float v = csum[tt][r];
            v += __shfl_xor(v, 1);
            v += __shfl_xor(v, 2);
            v += __shfl_xor(v, 4);
            v += __shfl_xor(v, 8);
            csum[tt][r] = v;
        }
    if (lr == 0) {
#pragma unroll
        for (int tt = 0; tt < 2; tt++)
#pragma unroll
            for (int r = 0; r < 4; r++)
                rcS[w * 32 + tt * 16 + lg * 4 + r] = 1.f / csum[tt][r];
    }
    __syncthreads();  // all MFMA reads of Qs done; rcS visible
    // ---- phase B: V rows [k0, k0+128) -> rc-scaled MFMA B-fragment blobs ----
#pragma unroll
    for (int it = 0; it < 4; it++) {
        int row = it * 32 + srow;
        int j = sj ^ (row & 7);
        GLD16(&QKV[(size_t)(b * NS + k0 + row) * N3 + 1024 + h * NDH + j * 8],
              &Qs[(it * 256 + w * 64) * 8]);
    }
    __syncthreads();
    // wave w = local 32-k slice; lane (lr,lg): blob element = V^T[nt*16+lr][w*32+lg*8+j]*rc
#pragma unroll
    for (int nt = 0; nt < 4; nt++) {
        int d = nt * 16 + lr;
        bf16 tmp[8];
#pragma unroll
        for (int j = 0; j < 8; j++) {
            int row = w * 32 + lg * 8 + j;
            float v = (float)Qs[row * 64 + (((d >> 3) ^ (row & 7)) * 8) + (d & 7)];
            tmp[j] = (bf16)(v * rcS[row]);
        }
        size_t blob = (size_t)((bh * 32 + kbidx * 4 + w) * 4 + nt);
        *(bf16x8*)&VB[blob * 512 + lane * 8] = *(bf16x8*)tmp;
    }
}

// ---- pass2 (q-tile 128): yb16 = E @ V' + x into QKV's dead V region.
//      K and V fragments both read from L2-hot blobs: NO LDS, NO barriers -----------------
__launch_bounds__(256)
__global__ void attn_fused(bf16* __restrict__ QKV, const bf16* __restrict__ VB,
                           const bf16* __restrict__ KB, const float* __restrict__ x,
                           float* __restrict__ bnSum, float* __restrict__ bnSumSq) {
    int bh = blockIdx.x, b = bh >> 3, h = bh & 7;
    int q0 = blockIdx.y * 128;
    int t = threadIdx.x, lane = t & 63, w = t >> 6;
    int lr = lane & 15, lg = lane >> 4;
    // Q fragments (B operand of swapped score mfma) in registers for whole kernel
    bf16x8 qf[2][2];
#pragma unroll
    for (int n = 0; n < 2; n++)
#pragma unroll
        for (int s = 0; s < 2; s++)
            qf[n][s] = *(const bf16x8*)&QKV[(size_t)(b * NS + q0 + w * 32 + n * 16 + lr) * N3 +
                                            h * NDH + s * 32 + lg * 8];
    const bf16* vbase = &VB[(size_t)(bh * 32) * 4 * 512 + lane * 8];
    const bf16* kbase = &KB[(size_t)(bh * 8) * 16 * 512 + lane * 8];
    floatx4 oacc[2][4] = {};
    const floatx4 zf = {};
    for (int kb = 0; kb < 8; kb++) {
        __builtin_amdgcn_s_setprio(1);
#pragma unroll
        for (int kt = 0; kt < 4; kt++) {
            bf16x8 kfr[2][2];
#pragma unroll
            for (int tt = 0; tt < 2; tt++)
#pragma unroll
                for (int s = 0; s < 2; s++)
                    kfr[tt][s] = *(const bf16x8*)&kbase[(size_t)(((kb * 4 + kt) * 4) +
                                                                 tt * 2 + s) * 512];
            bf16x8 vf[4];
#pragma unroll
            for (int nt = 0; nt < 4; nt++)
                vf[nt] = *(const bf16x8*)&vbase[(size_t)((kb * 4 + kt) * 4 + nt) * 512];
#pragma unroll
            for (int n = 0; n < 2; n++) {
                // swapped scores: C[m=k'][n=q], s' = s * KSCL already folded into K
                floatx4 s0 = mfma16(kfr[0][0], qf[n][0], zf);
                s0 = mfma16(kfr[0][1], qf[n][1], s0);
                floatx4 s1 = mfma16(kfr[1][0], qf[n][0], zf);
                s1 = mfma16(kfr[1][1], qf[n][1], s1);
                float e0[4], e1[4];
#pragma unroll
                for (int r = 0; r < 4; r++) {
                    e0[r] = fexp2(s0[r]);
                    e1[r] = fexp2(s1[r]);
                }
                // in-register transpose to PV A-fragment layout
                unsigned A0 = pack2(e0[0], e0[1]);
                unsigned A1 = pack2(e0[2], e0[3]);
                unsigned B0 = pack2(e1[0], e1[1]);
                unsigned B1 = pack2(e1[2], e1[3]);
                plane32(A0, B0); plane16(A0, B0);
                plane32(A1, B1); plane16(A1, B1);
                union { unsigned u[4]; bf16x8 v; } af;
                af.u[0] = A0; af.u[1] = A1; af.u[2] = B0; af.u[3] = B1;
#pragma unroll
                for (int nt = 0; nt < 4; nt++)
                    oacc[n][nt] = mfma16(af.v, vf[nt], oacc[n][nt]);
            }
        }
        __builtin_amdgcn_s_setprio(0);
    }
    // epilogue: yv = out + x; store bf16 into QKV's dead V region; BN partial sums
    float bs[4] = {}, bq2[4] = {};
#pragma unroll
    for (int n = 0; n < 2; n++)
#pragma unroll
        for (int nt = 0; nt < 4; nt++) {
            int d = nt * 16 + lr;
#pragma unroll
            for (int r = 0; r < 4; r++) {
                int q = q0 + w * 32 + n * 16 + lg * 4 + r;
                size_t row = (size_t)(b * NS + q);
                float yv = oacc[n][nt][r] + x[row * ND + h * NDH + d];
                QKV[row * N3 + 1024 + h * NDH + d] = (bf16)yv;  // yb16 stash (V is dead)
                bs[nt] += yv;
                bq2[nt] += yv * yv;
            }
        }
#pragma unroll
    for (int nt = 0; nt < 4; nt++) {
        float v = bs[nt], q2 = bq2[nt];
        v += __shfl_xor(v, 16); v += __shfl_xor(v, 32);
        q2 += __shfl_xor(q2, 16); q2 += __shfl_xor(q2, 32);
        if (lg == 0) {
            atomicAdd(&bnSum[h * NDH + nt * 16 + lr], v);
            atomicAdd(&bnSumSq[h * NDH + nt * 16 + lr], q2);
        }
    }
}

// ---------------- BN apply: read yb16 from QKV V-region, write fp32 d_out ----------------
__global__ void bn_apply(const bf16* __restrict__ QKV, float* __restrict__ y,
                         const float* __restrict__ bnSum, const float* __restrict__ bnSumSq,
                         const float* __restrict__ gamma, const float* __restrict__ beta) {
    int i = (blockIdx.x * 256 + threadIdx.x) * 8;
    int row = i >> 9, col = i & 511;
    bf16x8 yv = *(const bf16x8*)&QKV[(size_t)row * N3 + 1024 + col];
    float4 s0 = *(const float4*)&bnSum[col];
    float4 s1 = *(const float4*)&bnSum[col + 4];
    float4 q0 = *(const float4*)&bnSumSq[col];
    float4 q1 = *(const float4*)&bnSumSq[col + 4];
    float4 g0 = *(const float4*)&gamma[col];
    float4 g1 = *(const float4*)&gamma[col + 4];
    float4 b0 = *(const float4*)&beta[col];
    float4 b1 = *(const float4*)&beta[col + 4];
    float sm[8] = {s0.x, s0.y, s0.z, s0.w, s1.x, s1.y, s1.z, s1.w};
    float sq[8] = {q0.x, q0.y, q0.z, q0.w, q1.x, q1.y, q1.z, q1.w};
    float gm[8] = {g0.x, g0.y, g0.z, g0.w, g1.x, g1.y, g1.z, g1.w};
    float bt[8] = {b0.x, b0.y, b0.z, b0.w, b1.x, b1.y, b1.z, b1.w};
    float out[8];
#pragma unroll
    for (int j = 0; j < 8; j++) {
        float mean = sm[j] * (1.f / 8192.f);
        float var = sq[j] * (1.f / 8192.f) - mean * mean;
        float rstd = rsqrtf(var + 1e-5f);
        out[j] = ((float)yv[j] - mean) * rstd * gm[j] + bt[j];
    }
    *(float4*)&y[i] = make_float4(out[0], out[1], out[2], out[3]);
    *(float4*)&y[i + 4] = make_float4(out[4], out[5], out[6], out[7]);
}

extern "C" void kernel_launch(void* const* d_in, const int* in_sizes, int n_in,
                              void* d_out, int out_size, void* d_ws, size_t ws_size,
                              hipStream_t stream) {
    const float* x  = (const float*)d_in[0];
    const float* Wq = (const float*)d_in[1];
    const float* bq = (const float*)d_in[2];
    const float* Wk = (const float*)d_in[3];
    const float* bk = (const float*)d_in[4];
    const float* Wv = (const float*)d_in[5];
    const float* bv = (const float*)d_in[6];
    const float* gamma = (const float*)d_in[7];
    const float* beta  = (const float*)d_in[8];
    float* y = (float*)d_out;

    char* ws = (char*)d_ws;
    const size_t WB_OFF  = 0;
    const size_t QKV_OFF = 2u << 20;                          // 2 MiB
    const size_t VT_OFF  = QKV_OFF + (size_t)MROWS * N3 * 2;  // +24 MiB
    const size_t BN_OFF  = VT_OFF + (size_t)NBH * NDH * NS * 2;
    const size_t XB_OFF  = BN_OFF + (4u << 12);
    bf16*  Wb     = (bf16*)(ws + WB_OFF);
    bf16*  QKV    = (bf16*)(ws + QKV_OFF);
    bf16*  VB     = (bf16*)(ws + VT_OFF);
    float* bnSum  = (float*)(ws + BN_OFF);
    float* bnSumSq = bnSum + 512;
    bf16*  xb     = (bf16*)(ws + XB_OFF);
    bf16*  KB     = xb;  // xb is dead after gemm1; reuse its 8 MiB for K fragment blobs

    prep<<<2816, 256, 0, stream>>>(x, xb, bnSum, Wq, Wk, Wv, Wb);
    gemm1<<<dim3(64, 12), 256, 0, stream>>>(xb, Wb, bq, bk, bv, QKV);
    attn_colsum_vt<<<dim3(64, 8), 256, 0, stream>>>(QKV, VB, KB);
    attn_fused<<<dim3(64, 8), 256, 0, stream>>>(QKV, VB, KB, x, bnSum, bnSumSq);
    bn_apply<<<2048, 256, 0, stream>>>(QKV, y, bnSum, bnSumSq, gamma, beta);
}

// Round 16
// 81.885 us; speedup vs baseline: 1.0336x; 1.0336x over previous
//
#include <hip/hip_runtime.h>
#include <hip/hip_bf16.h>
#include <math.h>

typedef __bf16 bf16;
typedef __bf16 bf16x8 __attribute__((ext_vector_type(8)));
typedef float floatx4 __attribute__((ext_vector_type(4)));

#define NB 8
#define NS 1024
#define ND 512
#define NH 8
#define NDH 64
#define NBH 64
#define MROWS 8192
#define N3 1536
#define KSCL 0.18033688f  // 0.125 * log2(e): folded into K so exp(s/8)=exp2(s')

#define GLD16(src, dst)                                                            \
    __builtin_amdgcn_global_load_lds(                                              \
        (const __attribute__((address_space(1))) void*)(src),                      \
        (__attribute__((address_space(3))) void*)(dst), 16, 0, 0)

static __device__ __forceinline__ floatx4 mfma16(bf16x8 a, bf16x8 b, floatx4 c) {
    return __builtin_amdgcn_mfma_f32_16x16x32_bf16(a, b, c, 0, 0, 0);
}

// fast 2^x: raw v_exp_f32 (inputs here are bounded [0, ~12] — no edge cases)
static __device__ __forceinline__ float fexp2(float x) {
#if __has_builtin(__builtin_amdgcn_exp2f)
    return __builtin_amdgcn_exp2f(x);
#else
    return __expf(x * 0.69314718f);
#endif
}

static __device__ __forceinline__ unsigned pack2(float lo, float hi) {
    union { bf16 h[2]; unsigned u; } u;
    u.h[0] = (bf16)lo; u.h[1] = (bf16)hi;
    return u.u;
}

// non-volatile — pure value ops, scheduler may interleave chains
static __device__ __forceinline__ void plane32(unsigned &a, unsigned &b) {
    asm("v_permlane32_swap_b32 %0, %1" : "+v"(a), "+v"(b));
}
static __device__ __forceinline__ void plane16(unsigned &a, unsigned &b) {
    asm("v_permlane16_swap_b32 %0, %1" : "+v"(a), "+v"(b));
}

// ---- prep: [0,2048) x fp32->bf16 (+ zero BN accum); [2048,2816) W transpose+convert ----
__global__ void prep(const float* __restrict__ x, bf16* __restrict__ xb,
                     float* __restrict__ bnSum, const float* __restrict__ Wq,
                     const float* __restrict__ Wk, const float* __restrict__ Wv,
                     bf16* __restrict__ Wb) {
    __shared__ float tl[32][33];
    int bid = blockIdx.x;
    int t = threadIdx.x;
    if (bid < 2048) {
        if (bid == 0) {
            ((float4*)bnSum)[t] = make_float4(0.f, 0.f, 0.f, 0.f);  // 1024 floats
        }
        int i = (bid * 256 + t) * 8;
        float4 a = *(const float4*)&x[i];
        float4 b = *(const float4*)&x[i + 4];
        bf16 o[8] = {(bf16)a.x, (bf16)a.y, (bf16)a.z, (bf16)a.w,
                     (bf16)b.x, (bf16)b.y, (bf16)b.z, (bf16)b.w};
        *(bf16x8*)&xb[i] = *(bf16x8*)o;
    } else {
        int wbid = bid - 2048;
        int mat = wbid >> 8;          // 0..2
        int bx = wbid & 15;           // d0 / 32
        int by = (wbid >> 4) & 15;    // e0 / 32
        const float* W = mat == 0 ? Wq : (mat == 1 ? Wk : Wv);
        int d0 = bx * 32, e0 = by * 32;
        int tx = t & 31, ty = t >> 5;  // 32 x 8
#pragma unroll
        for (int i = 0; i < 4; i++) tl[ty * 4 + i][tx] = W[(d0 + ty * 4 + i) * ND + e0 + tx];
        __syncthreads();
#pragma unroll
        for (int i = 0; i < 4; i++)
            Wb[(mat * ND + e0 + ty * 4 + i) * ND + d0 + tx] = (bf16)tl[tx][ty * 4 + i];
    }
}

// ---------------- GEMM1: QKV = relu(xb @ Wb^T + b), K-cols pre-scaled by KSCL ------------
__launch_bounds__(256)
__global__ void gemm1(const bf16* __restrict__ xb, const bf16* __restrict__ Wb,
                      const float* __restrict__ bq, const float* __restrict__ bk,
                      const float* __restrict__ bv, bf16* __restrict__ QKV) {
    __shared__ __align__(16) bf16 As[128 * 64];
    __shared__ __align__(16) bf16 Bs[128 * 64];
    int t = threadIdx.x, lane = t & 63, w = t >> 6;
    int wr = w >> 1, wc = w & 1;
    int lr = lane & 15, lg = lane >> 4;
    int row0 = blockIdx.x * 128, col0 = blockIdx.y * 128;
    int srow = t >> 3, sj = t & 7;
    floatx4 acc[4][4] = {};
    for (int k0 = 0; k0 < ND; k0 += 64) {
        __syncthreads();
#pragma unroll
        for (int it = 0; it < 4; it++) {
            int row = it * 32 + srow;
            int j = sj ^ (row & 7);
            GLD16(&xb[(size_t)(row0 + row) * ND + k0 + j * 8], &As[(it * 256 + w * 64) * 8]);
            GLD16(&Wb[(size_t)(col0 + row) * ND + k0 + j * 8], &Bs[(it * 256 + w * 64) * 8]);
        }
        __syncthreads();
        bf16x8 af[2][4], bfr[2][4];
#pragma unroll
        for (int ks = 0; ks < 2; ks++) {
#pragma unroll
            for (int mt = 0; mt < 4; mt++)
                af[ks][mt] = *(const bf16x8*)&As[(wr * 64 + mt * 16 + lr) * 64 +
                                                 ((ks * 4 + lg) ^ (lr & 7)) * 8];
#pragma unroll
            for (int nt = 0; nt < 4; nt++)
                bfr[ks][nt] = *(const bf16x8*)&Bs[(wc * 64 + nt * 16 + lr) * 64 +
                                                  ((ks * 4 + lg) ^ (lr & 7)) * 8];
        }
#pragma unroll
        for (int ks = 0; ks < 2; ks++)
#pragma unroll
            for (int mt = 0; mt < 4; mt++)
#pragma unroll
                for (int nt = 0; nt < 4; nt++)
                    acc[mt][nt] = mfma16(af[ks][mt], bfr[ks][nt], acc[mt][nt]);
    }
#pragma unroll
    for (int mt = 0; mt < 4; mt++)
#pragma unroll
        for (int nt = 0; nt < 4; nt++) {
            int col = col0 + wc * 64 + nt * 16 + lr;
            float bias = col < 512 ? bq[col] : (col < 1024 ? bk[col - 512] : bv[col - 1024]);
            float scl = (col >= 512 && col < 1024) ? KSCL : 1.0f;
#pragma unroll
            for (int r = 0; r < 4; r++) {
                int row = row0 + wr * 64 + mt * 16 + lg * 4 + r;
                float v = acc[mt][nt][r] + bias;
                v = v > 0.f ? v : 0.f;
                v *= scl;
                QKV[(size_t)row * N3 + col] = (bf16)v;
            }
        }
}

// ---- colsum + V->fragment blobs (k-tile 128, grid (64,8)):
//      rc[k]=1/sum_q exp2(s'); VB blob[(bh*32+kt32)*4+nt][lane][8] = V^T*rc fragments ------
__launch_bounds__(256)
__global__ void attn_colsum_vt(const bf16* __restrict__ QKV, bf16* __restrict__ VB) {
    __shared__ __align__(16) bf16 Qs[128 * 64];  // 16 KB
    __shared__ float rcS[128];
    int bh = blockIdx.x, b = bh >> 3, h = bh & 7;
    int k0 = blockIdx.y * 128;
    int t = threadIdx.x, lane = t & 63, w = t >> 6;
    int lr = lane & 15, lg = lane >> 4;
    int srow = t >> 3, sj = t & 7;
    // K fragments (A operand of swapped mfma) held in registers for whole kernel
    bf16x8 kf[2][2];
#pragma unroll
    for (int tt = 0; tt < 2; tt++)
#pragma unroll
        for (int s = 0; s < 2; s++)
            kf[tt][s] = *(const bf16x8*)&QKV[(size_t)(b * NS + k0 + w * 32 + tt * 16 + lr) * N3 +
                                             512 + h * NDH + s * 32 + lg * 8];
    floatx4 csum[2] = {};
    const floatx4 zf = {};
    for (int qc = 0; qc < 8; qc++) {
        __syncthreads();
#pragma unroll
        for (int it = 0; it < 4; it++) {
            int row = it * 32 + srow;
            int j = sj ^ (row & 7);
            GLD16(&QKV[(size_t)(b * NS + qc * 128 + row) * N3 + h * NDH + j * 8],
                  &Qs[(it * 256 + w * 64) * 8]);
        }
        __syncthreads();
        __builtin_amdgcn_s_setprio(1);  // favor compute-phase waves vs staging-phase block
#pragma unroll
        for (int qt = 0; qt < 8; qt++) {
            bf16x8 qb0 = *(const bf16x8*)&Qs[(qt * 16 + lr) * 64 + (lg ^ (lr & 7)) * 8];
            bf16x8 qb1 = *(const bf16x8*)&Qs[(qt * 16 + lr) * 64 + ((4 + lg) ^ (lr & 7)) * 8];
#pragma unroll
            for (int tt = 0; tt < 2; tt++) {
                floatx4 a = mfma16(kf[tt][0], qb0, zf);
                a = mfma16(kf[tt][1], qb1, a);
#pragma unroll
                for (int r = 0; r < 4; r++) csum[tt][r] += fexp2(a[r]);
            }
        }
        __builtin_amdgcn_s_setprio(0);
    }
#pragma unroll
    for (int tt = 0; tt < 2; tt++)
#pragma unroll
        for (int r = 0; r < 4; r++) {
            float v = csum[tt][r];
            v += __shfl_xor(v, 1);
            v += __shfl_xor(v, 2);
            v += __shfl_xor(v, 4);
            v += __shfl_xor(v, 8);
            csum[tt][r] = v;
        }
    if (lr == 0) {
#pragma unroll
        for (int tt = 0; tt < 2; tt++)
#pragma unroll
            for (int r = 0; r < 4; r++)
                rcS[w * 32 + tt * 16 + lg * 4 + r] = 1.f / csum[tt][r];
    }
    __syncthreads();  // all MFMA reads of Qs done; rcS visible
    // ---- phase B: V rows [k0, k0+128) -> rc-scaled MFMA B-fragment blobs ----
#pragma unroll
    for (int it = 0; it < 4; it++) {
        int row = it * 32 + srow;
        int j = sj ^ (row & 7);
        GLD16(&QKV[(size_t)(b * NS + k0 + row) * N3 + 1024 + h * NDH + j * 8],
              &Qs[(it * 256 + w * 64) * 8]);
    }
    __syncthreads();
    // wave w = local 32-k slice; lane (lr,lg): blob element = V^T[nt*16+lr][w*32+lg*8+j]*rc
#pragma unroll
    for (int nt = 0; nt < 4; nt++) {
        int d = nt * 16 + lr;
        bf16 tmp[8];
#pragma unroll
        for (int j = 0; j < 8; j++) {
            int row = w * 32 + lg * 8 + j;
            float v = (float)Qs[row * 64 + (((d >> 3) ^ (row & 7)) * 8) + (d & 7)];
            tmp[j] = (bf16)(v * rcS[row]);
        }
        size_t blob = (size_t)((bh * 32 + (k0 >> 5) + w) * 4 + nt);
        *(bf16x8*)&VB[blob * 512 + lane * 8] = *(bf16x8*)tmp;
    }
}

// ---- pass2 (q-tile 128, K-tile 128): yb16 = E @ V' + x into QKV's dead V region;
//      V fragments read directly from VB blobs (L2-hot, no LDS staging) -------------------
__launch_bounds__(256)
__global__ void attn_fused(bf16* __restrict__ QKV, const bf16* __restrict__ VB,
                           const float* __restrict__ x,
                           float* __restrict__ bnSum, float* __restrict__ bnSumSq) {
    __shared__ __align__(16) bf16 Ks[128 * 64];  // 16 KB
    int bh = blockIdx.x, b = bh >> 3, h = bh & 7;
    int q0 = blockIdx.y * 128;
    int t = threadIdx.x, lane = t & 63, w = t >> 6;
    int lr = lane & 15, lg = lane >> 4;
    // Q fragments (B operand of swapped score mfma) in registers for whole kernel
    bf16x8 qf[2][2];
#pragma unroll
    for (int n = 0; n < 2; n++)
#pragma unroll
        for (int s = 0; s < 2; s++)
            qf[n][s] = *(const bf16x8*)&QKV[(size_t)(b * NS + q0 + w * 32 + n * 16 + lr) * N3 +
                                            h * NDH + s * 32 + lg * 8];
    const bf16* vbase = &VB[(size_t)(bh * 32) * 4 * 512 + lane * 8];
    int sKrow = t >> 3, sKj = t & 7;
    floatx4 oacc[2][4] = {};
    const floatx4 zf = {};
    for (int kb = 0; kb < 8; kb++) {
        int k0 = kb * 128;
        __syncthreads();
#pragma unroll
        for (int it = 0; it < 4; it++) {
            int rowK = it * 32 + sKrow;
            int jK = sKj ^ (rowK & 7);
            GLD16(&QKV[(size_t)(b * NS + k0 + rowK) * N3 + 512 + h * NDH + jK * 8],
                  &Ks[(it * 256 + w * 64) * 8]);
        }
        __syncthreads();
        __builtin_amdgcn_s_setprio(1);  // favor compute-phase waves vs staging-phase block
#pragma unroll
        for (int kt = 0; kt < 4; kt++) {
            bf16x8 kfr[2][2];
#pragma unroll
            for (int tt = 0; tt < 2; tt++)
#pragma unroll
                for (int s = 0; s < 2; s++)
                    kfr[tt][s] = *(const bf16x8*)&Ks[(kt * 32 + tt * 16 + lr) * 64 +
                                                     ((s * 4 + lg) ^ (lr & 7)) * 8];
            bf16x8 vf[4];
#pragma unroll
            for (int nt = 0; nt < 4; nt++)
                vf[nt] = *(const bf16x8*)&vbase[(size_t)((kb * 4 + kt) * 4 + nt) * 512];
#pragma unroll
            for (int n = 0; n < 2; n++) {
                // swapped scores: C[m=k'][n=q], s' = s * KSCL already folded into K
                floatx4 s0 = mfma16(kfr[0][0], qf[n][0], zf);
                s0 = mfma16(kfr[0][1], qf[n][1], s0);
                floatx4 s1 = mfma16(kfr[1][0], qf[n][0], zf);
                s1 = mfma16(kfr[1][1], qf[n][1], s1);
                float e0[4], e1[4];
#pragma unroll
                for (int r = 0; r < 4; r++) {
                    e0[r] = fexp2(s0[r]);
                    e1[r] = fexp2(s1[r]);
                }
                // in-register transpose to PV A-fragment layout
                unsigned A0 = pack2(e0[0], e0[1]);
                unsigned A1 = pack2(e0[2], e0[3]);
                unsigned B0 = pack2(e1[0], e1[1]);
                unsigned B1 = pack2(e1[2], e1[3]);
                plane32(A0, B0); plane16(A0, B0);
                plane32(A1, B1); plane16(A1, B1);
                union { unsigned u[4]; bf16x8 v; } af;
                af.u[0] = A0; af.u[1] = A1; af.u[2] = B0; af.u[3] = B1;
#pragma unroll
                for (int nt = 0; nt < 4; nt++)
                    oacc[n][nt] = mfma16(af.v, vf[nt], oacc[n][nt]);
            }
        }
        __builtin_amdgcn_s_setprio(0);
    }
    // epilogue: yv = out + x; store bf16 into QKV's dead V region; BN partial sums
    float bs[4] = {}, bq2[4] = {};
#pragma unroll
    for (int n = 0; n < 2; n++)
#pragma unroll
        for (int nt = 0; nt < 4; nt++) {
            int d = nt * 16 + lr;
#pragma unroll
            for (int r = 0; r < 4; r++) {
                int q = q0 + w * 32 + n * 16 + lg * 4 + r;
                size_t row = (size_t)(b * NS + q);
                float yv = oacc[n][nt][r] + x[row * ND + h * NDH + d];
                QKV[row * N3 + 1024 + h * NDH + d] = (bf16)yv;  // yb16 stash (V is dead)
                bs[nt] += yv;
                bq2[nt] += yv * yv;
            }
        }
#pragma unroll
    for (int nt = 0; nt < 4; nt++) {
        float v = bs[nt], q2 = bq2[nt];
        v += __shfl_xor(v, 16); v += __shfl_xor(v, 32);
        q2 += __shfl_xor(q2, 16); q2 += __shfl_xor(q2, 32);
        if (lg == 0) {
            atomicAdd(&bnSum[h * NDH + nt * 16 + lr], v);
            atomicAdd(&bnSumSq[h * NDH + nt * 16 + lr], q2);
        }
    }
}

// ---------------- BN apply: read yb16 from QKV V-region, write fp32 d_out ----------------
__global__ void bn_apply(const bf16* __restrict__ QKV, float* __restrict__ y,
                         const float* __restrict__ bnSum, const float* __restrict__ bnSumSq,
                         const float* __restrict__ gamma, const float* __restrict__ beta) {
    int i = (blockIdx.x * 256 + threadIdx.x) * 8;
    int row = i >> 9, col = i & 511;
    bf16x8 yv = *(const bf16x8*)&QKV[(size_t)row * N3 + 1024 + col];
    float4 s0 = *(const float4*)&bnSum[col];
    float4 s1 = *(const float4*)&bnSum[col + 4];
    float4 q0 = *(const float4*)&bnSumSq[col];
    float4 q1 = *(const float4*)&bnSumSq[col + 4];
    float4 g0 = *(const float4*)&gamma[col];
    float4 g1 = *(const float4*)&gamma[col + 4];
    float4 b0 = *(const float4*)&beta[col];
    float4 b1 = *(const float4*)&beta[col + 4];
    float sm[8] = {s0.x, s0.y, s0.z, s0.w, s1.x, s1.y, s1.z, s1.w};
    float sq[8] = {q0.x, q0.y, q0.z, q0.w, q1.x, q1.y, q1.z, q1.w};
    float gm[8] = {g0.x, g0.y, g0.z, g0.w, g1.x, g1.y, g1.z, g1.w};
    float bt[8] = {b0.x, b0.y, b0.z, b0.w, b1.x, b1.y, b1.z, b1.w};
    float out[8];
#pragma unroll
    for (int j = 0; j < 8; j++) {
        float mean = sm[j] * (1.f / 8192.f);
        float var = sq[j] * (1.f / 8192.f) - mean * mean;
        float rstd = rsqrtf(var + 1e-5f);
        out[j] = ((float)yv[j] - mean) * rstd * gm[j] + bt[j];
    }
    *(float4*)&y[i] = make_float4(out[0], out[1], out[2], out[3]);
    *(float4*)&y[i + 4] = make_float4(out[4], out[5], out[6], out[7]);
}

extern "C" void kernel_launch(void* const* d_in, const int* in_sizes, int n_in,
                              void* d_out, int out_size, void* d_ws, size_t ws_size,
                              hipStream_t stream) {
    const float* x  = (const float*)d_in[0];
    const float* Wq = (const float*)d_in[1];
    const float* bq = (const float*)d_in[2];
    const float* Wk = (const float*)d_in[3];
    const float* bk = (const float*)d_in[4];
    const float* Wv = (const float*)d_in[5];
    const float* bv = (const float*)d_in[6];
    const float* gamma = (const float*)d_in[7];
    const float* beta  = (const float*)d_in[8];
    float* y = (float*)d_out;

    char* ws = (char*)d_ws;
    const size_t WB_OFF  = 0;
    const size_t QKV_OFF = 2u << 20;                          // 2 MiB
    const size_t VT_OFF  = QKV_OFF + (size_t)MROWS * N3 * 2;  // +24 MiB
    const size_t BN_OFF  = VT_OFF + (size_t)NBH * NDH * NS * 2;
    const size_t XB_OFF  = BN_OFF + (4u << 12);
    bf16*  Wb     = (bf16*)(ws + WB_OFF);
    bf16*  QKV    = (bf16*)(ws + QKV_OFF);
    bf16*  VB     = (bf16*)(ws + VT_OFF);
    float* bnSum  = (float*)(ws + BN_OFF);
    float* bnSumSq = bnSum + 512;
    bf16*  xb     = (bf16*)(ws + XB_OFF);

    prep<<<2816, 256, 0, stream>>>(x, xb, bnSum, Wq, Wk, Wv, Wb);
    gemm1<<<dim3(64, 12), 256, 0, stream>>>(xb, Wb, bq, bk, bv, QKV);
    attn_colsum_vt<<<dim3(64, 8), 256, 0, stream>>>(QKV, VB);
    attn_fused<<<dim3(64, 8), 256, 0, stream>>>(QKV, VB, x, bnSum, bnSumSq);
    bn_apply<<<2048, 256, 0, stream>>>(QKV, y, bnSum, bnSumSq, gamma, beta);
}

// Round 17
// 81.747 us; speedup vs baseline: 1.0354x; 1.0017x over previous
//
#include <hip/hip_runtime.h>
#include <hip/hip_bf16.h>
#include <math.h>

typedef __bf16 bf16;
typedef __bf16 bf16x8 __attribute__((ext_vector_type(8)));
typedef float floatx4 __attribute__((ext_vector_type(4)));

#define NB 8
#define NS 1024
#define ND 512
#define NH 8
#define NDH 64
#define NBH 64
#define MROWS 8192
#define N3 1536
#define KSCL 0.18033688f  // 0.125 * log2(e): folded into K so exp(s/8)=exp2(s')

#define GLD16(src, dst)                                                            \
    __builtin_amdgcn_global_load_lds(                                              \
        (const __attribute__((address_space(1))) void*)(src),                      \
        (__attribute__((address_space(3))) void*)(dst), 16, 0, 0)

static __device__ __forceinline__ floatx4 mfma16(bf16x8 a, bf16x8 b, floatx4 c) {
    return __builtin_amdgcn_mfma_f32_16x16x32_bf16(a, b, c, 0, 0, 0);
}

// fast 2^x: raw v_exp_f32 (inputs here are bounded [0, ~12] — no edge cases)
static __device__ __forceinline__ float fexp2(float x) {
#if __has_builtin(__builtin_amdgcn_exp2f)
    return __builtin_amdgcn_exp2f(x);
#else
    return __expf(x * 0.69314718f);
#endif
}

static __device__ __forceinline__ unsigned pack2(float lo, float hi) {
    union { bf16 h[2]; unsigned u; } u;
    u.h[0] = (bf16)lo; u.h[1] = (bf16)hi;
    return u.u;
}

// non-volatile — pure value ops, scheduler may interleave chains
static __device__ __forceinline__ void plane32(unsigned &a, unsigned &b) {
    asm("v_permlane32_swap_b32 %0, %1" : "+v"(a), "+v"(b));
}
static __device__ __forceinline__ void plane16(unsigned &a, unsigned &b) {
    asm("v_permlane16_swap_b32 %0, %1" : "+v"(a), "+v"(b));
}

// ---- prep: [0,2048) x fp32->bf16 (+ zero BN accum); [2048,2816) W transpose+convert ----
__global__ void prep(const float* __restrict__ x, bf16* __restrict__ xb,
                     float* __restrict__ bnSum, const float* __restrict__ Wq,
                     const float* __restrict__ Wk, const float* __restrict__ Wv,
                     bf16* __restrict__ Wb) {
    __shared__ float tl[32][33];
    int bid = blockIdx.x;
    int t = threadIdx.x;
    if (bid < 2048) {
        if (bid == 0) {
            ((float4*)bnSum)[t] = make_float4(0.f, 0.f, 0.f, 0.f);  // 1024 floats
        }
        int i = (bid * 256 + t) * 8;
        float4 a = *(const float4*)&x[i];
        float4 b = *(const float4*)&x[i + 4];
        bf16 o[8] = {(bf16)a.x, (bf16)a.y, (bf16)a.z, (bf16)a.w,
                     (bf16)b.x, (bf16)b.y, (bf16)b.z, (bf16)b.w};
        *(bf16x8*)&xb[i] = *(bf16x8*)o;
    } else {
        int wbid = bid - 2048;
        int mat = wbid >> 8;          // 0..2
        int bx = wbid & 15;           // d0 / 32
        int by = (wbid >> 4) & 15;    // e0 / 32
        const float* W = mat == 0 ? Wq : (mat == 1 ? Wk : Wv);
        int d0 = bx * 32, e0 = by * 32;
        int tx = t & 31, ty = t >> 5;  // 32 x 8
#pragma unroll
        for (int i = 0; i < 4; i++) tl[ty * 4 + i][tx] = W[(d0 + ty * 4 + i) * ND + e0 + tx];
        __syncthreads();
#pragma unroll
        for (int i = 0; i < 4; i++)
            Wb[(mat * ND + e0 + ty * 4 + i) * ND + d0 + tx] = (bf16)tl[tx][ty * 4 + i];
    }
}

// ---------------- GEMM1: QKV = relu(xb @ Wb^T + b), K-cols pre-scaled by KSCL ------------
__launch_bounds__(256)
__global__ void gemm1(const bf16* __restrict__ xb, const bf16* __restrict__ Wb,
                      const float* __restrict__ bq, const float* __restrict__ bk,
                      const float* __restrict__ bv, bf16* __restrict__ QKV) {
    __shared__ __align__(16) bf16 As[128 * 64];
    __shared__ __align__(16) bf16 Bs[128 * 64];
    int t = threadIdx.x, lane = t & 63, w = t >> 6;
    int wr = w >> 1, wc = w & 1;
    int lr = lane & 15, lg = lane >> 4;
    int row0 = blockIdx.x * 128, col0 = blockIdx.y * 128;
    int srow = t >> 3, sj = t & 7;
    floatx4 acc[4][4] = {};
    for (int k0 = 0; k0 < ND; k0 += 64) {
        __syncthreads();
#pragma unroll
        for (int it = 0; it < 4; it++) {
            int row = it * 32 + srow;
            int j = sj ^ (row & 7);
            GLD16(&xb[(size_t)(row0 + row) * ND + k0 + j * 8], &As[(it * 256 + w * 64) * 8]);
            GLD16(&Wb[(size_t)(col0 + row) * ND + k0 + j * 8], &Bs[(it * 256 + w * 64) * 8]);
        }
        __syncthreads();
        bf16x8 af[2][4], bfr[2][4];
#pragma unroll
        for (int ks = 0; ks < 2; ks++) {
#pragma unroll
            for (int mt = 0; mt < 4; mt++)
                af[ks][mt] = *(const bf16x8*)&As[(wr * 64 + mt * 16 + lr) * 64 +
                                                 ((ks * 4 + lg) ^ (lr & 7)) * 8];
#pragma unroll
            for (int nt = 0; nt < 4; nt++)
                bfr[ks][nt] = *(const bf16x8*)&Bs[(wc * 64 + nt * 16 + lr) * 64 +
                                                  ((ks * 4 + lg) ^ (lr & 7)) * 8];
        }
#pragma unroll
        for (int ks = 0; ks < 2; ks++)
#pragma unroll
            for (int mt = 0; mt < 4; mt++)
#pragma unroll
                for (int nt = 0; nt < 4; nt++)
                    acc[mt][nt] = mfma16(af[ks][mt], bfr[ks][nt], acc[mt][nt]);
    }
#pragma unroll
    for (int mt = 0; mt < 4; mt++)
#pragma unroll
        for (int nt = 0; nt < 4; nt++) {
            int col = col0 + wc * 64 + nt * 16 + lr;
            float bias = col < 512 ? bq[col] : (col < 1024 ? bk[col - 512] : bv[col - 1024]);
            float scl = (col >= 512 && col < 1024) ? KSCL : 1.0f;
#pragma unroll
            for (int r = 0; r < 4; r++) {
                int row = row0 + wr * 64 + mt * 16 + lg * 4 + r;
                float v = acc[mt][nt][r] + bias;
                v = v > 0.f ? v : 0.f;
                v *= scl;
                QKV[(size_t)row * N3 + col] = (bf16)v;
            }
        }
}

// ---- colsum + V->fragment blobs (k-tile 128, grid (64,8)):
//      rc[k]=1/sum_q exp2(s'); VB blob[(bh*32+kt32)*4+nt][lane][8] = V^T*rc fragments ------
__launch_bounds__(256)
__global__ void attn_colsum_vt(const bf16* __restrict__ QKV, bf16* __restrict__ VB) {
    __shared__ __align__(16) bf16 Qs[128 * 64];  // 16 KB
    __shared__ float rcS[128];
    int bh = blockIdx.x, b = bh >> 3, h = bh & 7;
    int k0 = blockIdx.y * 128;
    int t = threadIdx.x, lane = t & 63, w = t >> 6;
    int lr = lane & 15, lg = lane >> 4;
    int srow = t >> 3, sj = t & 7;
    // K fragments (A operand of swapped mfma) held in registers for whole kernel
    bf16x8 kf[2][2];
#pragma unroll
    for (int tt = 0; tt < 2; tt++)
#pragma unroll
        for (int s = 0; s < 2; s++)
            kf[tt][s] = *(const bf16x8*)&QKV[(size_t)(b * NS + k0 + w * 32 + tt * 16 + lr) * N3 +
                                             512 + h * NDH + s * 32 + lg * 8];
    floatx4 csum[2] = {};
    const floatx4 zf = {};
    for (int qc = 0; qc < 8; qc++) {
        __syncthreads();
#pragma unroll
        for (int it = 0; it < 4; it++) {
            int row = it * 32 + srow;
            int j = sj ^ (row & 7);
            GLD16(&QKV[(size_t)(b * NS + qc * 128 + row) * N3 + h * NDH + j * 8],
                  &Qs[(it * 256 + w * 64) * 8]);
        }
        __syncthreads();
        __builtin_amdgcn_s_setprio(1);  // favor compute-phase waves vs staging-phase block
#pragma unroll
        for (int qt = 0; qt < 8; qt++) {
            bf16x8 qb0 = *(const bf16x8*)&Qs[(qt * 16 + lr) * 64 + (lg ^ (lr & 7)) * 8];
            bf16x8 qb1 = *(const bf16x8*)&Qs[(qt * 16 + lr) * 64 + ((4 + lg) ^ (lr & 7)) * 8];
#pragma unroll
            for (int tt = 0; tt < 2; tt++) {
                floatx4 a = mfma16(kf[tt][0], qb0, zf);
                a = mfma16(kf[tt][1], qb1, a);
#pragma unroll
                for (int r = 0; r < 4; r++) csum[tt][r] += fexp2(a[r]);
            }
        }
        __builtin_amdgcn_s_setprio(0);
    }
#pragma unroll
    for (int tt = 0; tt < 2; tt++)
#pragma unroll
        for (int r = 0; r < 4; r++) {
            float v = csum[tt][r];
            v += __shfl_xor(v, 1);
            v += __shfl_xor(v, 2);
            v += __shfl_xor(v, 4);
            v += __shfl_xor(v, 8);
            csum[tt][r] = v;
        }
    if (lr == 0) {
#pragma unroll
        for (int tt = 0; tt < 2; tt++)
#pragma unroll
            for (int r = 0; r < 4; r++)
                rcS[w * 32 + tt * 16 + lg * 4 + r] = 1.f / csum[tt][r];
    }
    __syncthreads();  // all MFMA reads of Qs done; rcS visible
    // ---- phase B: V rows [k0, k0+128) -> rc-scaled MFMA B-fragment blobs ----
#pragma unroll
    for (int it = 0; it < 4; it++) {
        int row = it * 32 + srow;
        int j = sj ^ (row & 7);
        GLD16(&QKV[(size_t)(b * NS + k0 + row) * N3 + 1024 + h * NDH + j * 8],
              &Qs[(it * 256 + w * 64) * 8]);
    }
    __syncthreads();
    // wave w = local 32-k slice; lane (lr,lg): blob element = V^T[nt*16+lr][w*32+lg*8+j]*rc
#pragma unroll
    for (int nt = 0; nt < 4; nt++) {
        int d = nt * 16 + lr;
        bf16 tmp[8];
#pragma unroll
        for (int j = 0; j < 8; j++) {
            int row = w * 32 + lg * 8 + j;
            float v = (float)Qs[row * 64 + (((d >> 3) ^ (row & 7)) * 8) + (d & 7)];
            tmp[j] = (bf16)(v * rcS[row]);
        }
        size_t blob = (size_t)((bh * 32 + (k0 >> 5) + w) * 4 + nt);
        *(bf16x8*)&VB[blob * 512 + lane * 8] = *(bf16x8*)tmp;
    }
}

// ---- pass2 (q-tile 128, K-tile 128): yb16 = E @ V' + xb into QKV's dead V region;
//      V fragments read directly from VB blobs (L2-hot, no LDS staging) -------------------
__launch_bounds__(256)
__global__ void attn_fused(bf16* __restrict__ QKV, const bf16* __restrict__ VB,
                           const bf16* __restrict__ xb,
                           float* __restrict__ bnSum, float* __restrict__ bnSumSq) {
    __shared__ __align__(16) bf16 Ks[128 * 64];  // 16 KB
    int bh = blockIdx.x, b = bh >> 3, h = bh & 7;
    int q0 = blockIdx.y * 128;
    int t = threadIdx.x, lane = t & 63, w = t >> 6;
    int lr = lane & 15, lg = lane >> 4;
    // Q fragments (B operand of swapped score mfma) in registers for whole kernel
    bf16x8 qf[2][2];
#pragma unroll
    for (int n = 0; n < 2; n++)
#pragma unroll
        for (int s = 0; s < 2; s++)
            qf[n][s] = *(const bf16x8*)&QKV[(size_t)(b * NS + q0 + w * 32 + n * 16 + lr) * N3 +
                                            h * NDH + s * 32 + lg * 8];
    const bf16* vbase = &VB[(size_t)(bh * 32) * 4 * 512 + lane * 8];
    int sKrow = t >> 3, sKj = t & 7;
    floatx4 oacc[2][4] = {};
    const floatx4 zf = {};
    for (int kb = 0; kb < 8; kb++) {
        int k0 = kb * 128;
        __syncthreads();
#pragma unroll
        for (int it = 0; it < 4; it++) {
            int rowK = it * 32 + sKrow;
            int jK = sKj ^ (rowK & 7);
            GLD16(&QKV[(size_t)(b * NS + k0 + rowK) * N3 + 512 + h * NDH + jK * 8],
                  &Ks[(it * 256 + w * 64) * 8]);
        }
        __syncthreads();
        __builtin_amdgcn_s_setprio(1);  // favor compute-phase waves vs staging-phase block
#pragma unroll
        for (int kt = 0; kt < 4; kt++) {
            bf16x8 kfr[2][2];
#pragma unroll
            for (int tt = 0; tt < 2; tt++)
#pragma unroll
                for (int s = 0; s < 2; s++)
                    kfr[tt][s] = *(const bf16x8*)&Ks[(kt * 32 + tt * 16 + lr) * 64 +
                                                     ((s * 4 + lg) ^ (lr & 7)) * 8];
            bf16x8 vf[4];
#pragma unroll
            for (int nt = 0; nt < 4; nt++)
                vf[nt] = *(const bf16x8*)&vbase[(size_t)((kb * 4 + kt) * 4 + nt) * 512];
#pragma unroll
            for (int n = 0; n < 2; n++) {
                // swapped scores: C[m=k'][n=q], s' = s * KSCL already folded into K
                floatx4 s0 = mfma16(kfr[0][0], qf[n][0], zf);
                s0 = mfma16(kfr[0][1], qf[n][1], s0);
                floatx4 s1 = mfma16(kfr[1][0], qf[n][0], zf);
                s1 = mfma16(kfr[1][1], qf[n][1], s1);
                float e0[4], e1[4];
#pragma unroll
                for (int r = 0; r < 4; r++) {
                    e0[r] = fexp2(s0[r]);
                    e1[r] = fexp2(s1[r]);
                }
                // in-register transpose to PV A-fragment layout
                unsigned A0 = pack2(e0[0], e0[1]);
                unsigned A1 = pack2(e0[2], e0[3]);
                unsigned B0 = pack2(e1[0], e1[1]);
                unsigned B1 = pack2(e1[2], e1[3]);
                plane32(A0, B0); plane16(A0, B0);
                plane32(A1, B1); plane16(A1, B1);
                union { unsigned u[4]; bf16x8 v; } af;
                af.u[0] = A0; af.u[1] = A1; af.u[2] = B0; af.u[3] = B1;
#pragma unroll
                for (int nt = 0; nt < 4; nt++)
                    oacc[n][nt] = mfma16(af.v, vf[nt], oacc[n][nt]);
            }
        }
        __builtin_amdgcn_s_setprio(0);
    }
    // epilogue: yv = out + xb (bf16 residual); store bf16 into QKV's dead V region; BN sums
    float bs[4] = {}, bq2[4] = {};
#pragma unroll
    for (int n = 0; n < 2; n++)
#pragma unroll
        for (int nt = 0; nt < 4; nt++) {
            int d = nt * 16 + lr;
#pragma unroll
            for (int r = 0; r < 4; r++) {
                int q = q0 + w * 32 + n * 16 + lg * 4 + r;
                size_t row = (size_t)(b * NS + q);
                float yv = oacc[n][nt][r] + (float)xb[row * ND + h * NDH + d];
                QKV[row * N3 + 1024 + h * NDH + d] = (bf16)yv;  // yb16 stash (V is dead)
                bs[nt] += yv;
                bq2[nt] += yv * yv;
            }
        }
#pragma unroll
    for (int nt = 0; nt < 4; nt++) {
        float v = bs[nt], q2 = bq2[nt];
        v += __shfl_xor(v, 16); v += __shfl_xor(v, 32);
        q2 += __shfl_xor(q2, 16); q2 += __shfl_xor(q2, 32);
        if (lg == 0) {
            atomicAdd(&bnSum[h * NDH + nt * 16 + lr], v);
            atomicAdd(&bnSumSq[h * NDH + nt * 16 + lr], q2);
        }
    }
}

// ---------------- BN apply: read yb16 from QKV V-region, write fp32 d_out ----------------
__global__ void bn_apply(const bf16* __restrict__ QKV, float* __restrict__ y,
                         const float* __restrict__ bnSum, const float* __restrict__ bnSumSq,
                         const float* __restrict__ gamma, const float* __restrict__ beta) {
    int i = (blockIdx.x * 256 + threadIdx.x) * 8;
    int row = i >> 9, col = i & 511;
    bf16x8 yv = *(const bf16x8*)&QKV[(size_t)row * N3 + 1024 + col];
    float4 s0 = *(const float4*)&bnSum[col];
    float4 s1 = *(const float4*)&bnSum[col + 4];
    float4 q0 = *(const float4*)&bnSumSq[col];
    float4 q1 = *(const float4*)&bnSumSq[col + 4];
    float4 g0 = *(const float4*)&gamma[col];
    float4 g1 = *(const float4*)&gamma[col + 4];
    float4 b0 = *(const float4*)&beta[col];
    float4 b1 = *(const float4*)&beta[col + 4];
    float sm[8] = {s0.x, s0.y, s0.z, s0.w, s1.x, s1.y, s1.z, s1.w};
    float sq[8] = {q0.x, q0.y, q0.z, q0.w, q1.x, q1.y, q1.z, q1.w};
    float gm[8] = {g0.x, g0.y, g0.z, g0.w, g1.x, g1.y, g1.z, g1.w};
    float bt[8] = {b0.x, b0.y, b0.z, b0.w, b1.x, b1.y, b1.z, b1.w};
    float out[8];
#pragma unroll
    for (int j = 0; j < 8; j++) {
        float mean = sm[j] * (1.f / 8192.f);
        float var = sq[j] * (1.f / 8192.f) - mean * mean;
        float rstd = rsqrtf(var + 1e-5f);
        out[j] = ((float)yv[j] - mean) * rstd * gm[j] + bt[j];
    }
    *(float4*)&y[i] = make_float4(out[0], out[1], out[2], out[3]);
    *(float4*)&y[i + 4] = make_float4(out[4], out[5], out[6], out[7]);
}

extern "C" void kernel_launch(void* const* d_in, const int* in_sizes, int n_in,
                              void* d_out, int out_size, void* d_ws, size_t ws_size,
                              hipStream_t stream) {
    const float* x  = (const float*)d_in[0];
    const float* Wq = (const float*)d_in[1];
    const float* bq = (const float*)d_in[2];
    const float* Wk = (const float*)d_in[3];
    const float* bk = (const float*)d_in[4];
    const float* Wv = (const float*)d_in[5];
    const float* bv = (const float*)d_in[6];
    const float* gamma = (const float*)d_in[7];
    const float* beta  = (const float*)d_in[8];
    float* y = (float*)d_out;

    char* ws = (char*)d_ws;
    const size_t WB_OFF  = 0;
    const size_t QKV_OFF = 2u << 20;                          // 2 MiB
    const size_t VT_OFF  = QKV_OFF + (size_t)MROWS * N3 * 2;  // +24 MiB
    const size_t BN_OFF  = VT_OFF + (size_t)NBH * NDH * NS * 2;
    const size_t XB_OFF  = BN_OFF + (4u << 12);
    bf16*  Wb     = (bf16*)(ws + WB_OFF);
    bf16*  QKV    = (bf16*)(ws + QKV_OFF);
    bf16*  VB     = (bf16*)(ws + VT_OFF);
    float* bnSum  = (float*)(ws + BN_OFF);
    float* bnSumSq = bnSum + 512;
    bf16*  xb     = (bf16*)(ws + XB_OFF);

    prep<<<2816, 256, 0, stream>>>(x, xb, bnSum, Wq, Wk, Wv, Wb);
    gemm1<<<dim3(64, 12), 256, 0, stream>>>(xb, Wb, bq, bk, bv, QKV);
    attn_colsum_vt<<<dim3(64, 8), 256, 0, stream>>>(QKV, VB);
    attn_fused<<<dim3(64, 8), 256, 0, stream>>>(QKV, VB, xb, bnSum, bnSumSq);
    bn_apply<<<2048, 256, 0, stream>>>(QKV, y, bnSum, bnSumSq, gamma, beta);
}